// Round 8
// baseline (429.896 us; speedup 1.0000x reference)
//
#include <hip/hip_runtime.h>

// Problem constants
#define BB 4
#define SS 2048
#define DD 1024   // DIM_IN = DIM_Q = DIM_V = 1024

typedef __attribute__((ext_vector_type(8))) short short8;
typedef __attribute__((ext_vector_type(4))) float f32x4;

__device__ __forceinline__ unsigned short f2b(float f) {
  unsigned u = __builtin_bit_cast(unsigned, f);
  u += 0x7fffu + ((u >> 16) & 1u);   // RNE
  return (unsigned short)(u >> 16);
}
__device__ __forceinline__ float b2f(unsigned short us) {
  unsigned u = (unsigned)us << 16;
  return __builtin_bit_cast(float, u);
}

__device__ __forceinline__ void gl2lds16(const void* g, void* l) {
  __builtin_amdgcn_global_load_lds(
      (__attribute__((address_space(1))) unsigned int*)(void*)(size_t)(uintptr_t)g,
      (__attribute__((address_space(3))) unsigned int*)l, 16, 0, 0);
}

__device__ __forceinline__ uint4 cvt8(float4 a, float4 b) {
  union { unsigned short us[8]; uint4 v; } o;
  o.us[0] = f2b(a.x); o.us[1] = f2b(a.y); o.us[2] = f2b(a.z); o.us[3] = f2b(a.w);
  o.us[4] = f2b(b.x); o.us[5] = f2b(b.y); o.us[6] = f2b(b.z); o.us[7] = f2b(b.w);
  return o.v;
}

// ============ fused f32-input projection GEMM (replaces cvt_all + 2 GEMMs) ==
// One dispatch, grid (64,8,3):
//   z=0: qb[m][f] = sum_d query[m][d]*Wq[f][d] + bq[f]    (bm=x*128, bn=y*128)
//   z=1: kb[m][f] = ... key/Wk/bk
//   z=2: vT[n][m] = sum_d Wv[n][d]*value[m][d] + bv[n]    (bm=y*128, bn=x*128,
//        ldc=8192, row-bias)
// Inputs are read as f32 and converted to bf16 DURING staging (reg-staging:
// 2xfloat4 load -> f2b pack -> ds_write_b128 per operand-half). This removes
// the standalone cvt_all dispatch (~50us) entirely. Proj GEMMs are ~28% HBM,
// so the 2x staging bytes are free; the cvt VALU (~32 f2b/thread/K-step)
// overlaps MFMA across the 2 resident blocks/CU (m114).
// Pipeline (reads-before-stage invariant kept; loads go to REGISTERS so
// there is no LDS-DMA/ds_read alias drain at all):
//   syncthreads -> ds_read frags(cur) -> [SB0] glb f32 loads(next)
//   -> [SB0] 16 MFMA -> [SB0] cvt+ds_write(cur^1) -> loop
// Hazards purely via __syncthreads (drains lgkm: all waves' ds_writes done
// before any wave's next-iter reads; write target is the opposite buffer).
__global__ __launch_bounds__(256, 2) void proj_f32(
    const float* __restrict__ query, const float* __restrict__ key,
    const float* __restrict__ value,
    const float* __restrict__ Wq, const float* __restrict__ Wk,
    const float* __restrict__ Wv,
    const float* __restrict__ bq, const float* __restrict__ bk,
    const float* __restrict__ bv,
    unsigned short* __restrict__ qkb,   // qb at +0, kb at +8388608 shorts
    unsigned short* __restrict__ vT) {
  __shared__ unsigned short sA[2][128 * 32];
  __shared__ unsigned short sB[2][128 * 32];
  const int tid  = threadIdx.x;
  const int wave = tid >> 6;
  const int lane = tid & 63;
  const int l15  = lane & 15;
  const int quad = lane >> 4;
  const int waveR = wave >> 1, waveC = wave & 1;
  const int z = blockIdx.z;

  const float* Ap; const float* Bp; const float* bp;
  unsigned short* C; int ldc, bm, bn; bool rowb;
  if (z == 2) {
    Ap = Wv; Bp = value; bp = bv; C = vT; ldc = 8192; rowb = true;
    bm = blockIdx.y * 128; bn = blockIdx.x * 128;
  } else {
    Ap = z ? key : query; Bp = z ? Wk : Wq; bp = z ? bk : bq;
    C = qkb + (size_t)z * 8388608; ldc = 1024; rowb = false;
    bm = blockIdx.x * 128; bn = blockIdx.y * 128;
  }

  // Stage geometry (identical LDS layout to the gl2lds version):
  // thread handles rows {tid>>2, tid>>2 + 64}, cols (tid&3)*8 .. +8.
  const int srow = tid >> 2, cgrp = (tid & 3) * 8;
  const float* gA0 = Ap + (size_t)(bm + srow) * 1024 + cgrp;
  const float* gA1 = gA0 + (size_t)64 * 1024;
  const float* gB0 = Bp + (size_t)(bn + srow) * 1024 + cgrp;
  const float* gB1 = gB0 + (size_t)64 * 1024;

  f32x4 acc[4][4] = {};
  const int aro = (waveR * 64 + l15) * 32 + quad * 8;
  const int bro = (waveC * 64 + l15) * 32 + quad * 8;

  // Prologue: stage K-tile 0 into buffer 0 through registers.
  {
    float4 a0 = *(const float4*)gA0, a1 = *(const float4*)(gA0 + 4);
    float4 a2 = *(const float4*)gA1, a3 = *(const float4*)(gA1 + 4);
    float4 b0 = *(const float4*)gB0, b1 = *(const float4*)(gB0 + 4);
    float4 b2 = *(const float4*)gB1, b3 = *(const float4*)(gB1 + 4);
    *(uint4*)(sA[0] + tid * 8)        = cvt8(a0, a1);
    *(uint4*)(sA[0] + tid * 8 + 2048) = cvt8(a2, a3);
    *(uint4*)(sB[0] + tid * 8)        = cvt8(b0, b1);
    *(uint4*)(sB[0] + tid * 8 + 2048) = cvt8(b2, b3);
  }
  int cur = 0;

  for (int kt = 0; kt < 1024; kt += 32) {
    __syncthreads();                 // buf[cur] published (lgkm drain+barrier)
    short8 af[4], bf[4];
#pragma unroll
    for (int i = 0; i < 4; ++i) af[i] = *(const short8*)(sA[cur] + aro + i * 16 * 32);
#pragma unroll
    for (int j = 0; j < 4; ++j) bf[j] = *(const short8*)(sB[cur] + bro + j * 16 * 32);
    __builtin_amdgcn_sched_barrier(0);   // frag reads issued first
    const bool pf = (kt + 32) < 1024;
    float4 a0, a1, a2, a3, b0, b1, b2, b3;
    if (pf) {
      const int o = kt + 32;
      a0 = *(const float4*)(gA0 + o); a1 = *(const float4*)(gA0 + o + 4);
      a2 = *(const float4*)(gA1 + o); a3 = *(const float4*)(gA1 + o + 4);
      b0 = *(const float4*)(gB0 + o); b1 = *(const float4*)(gB0 + o + 4);
      b2 = *(const float4*)(gB1 + o); b3 = *(const float4*)(gB1 + o + 4);
    }
    __builtin_amdgcn_sched_barrier(0);   // loads issued before MFMA cluster
#pragma unroll
    for (int i = 0; i < 4; ++i)
#pragma unroll
      for (int j = 0; j < 4; ++j)
        acc[i][j] = __builtin_amdgcn_mfma_f32_16x16x32_bf16(af[i], bf[j], acc[i][j], 0, 0, 0);
    __builtin_amdgcn_sched_barrier(0);   // cvt+write after MFMA (hides vmcnt)
    if (pf) {
      unsigned short* dA = sA[cur ^ 1];
      unsigned short* dB = sB[cur ^ 1];
      *(uint4*)(dA + tid * 8)        = cvt8(a0, a1);
      *(uint4*)(dA + tid * 8 + 2048) = cvt8(a2, a3);
      *(uint4*)(dB + tid * 8)        = cvt8(b0, b1);
      *(uint4*)(dB + tid * 8 + 2048) = cvt8(b2, b3);
    }
    cur ^= 1;
  }

  // C/D layout: col = lane&15, row = quad*4 + reg
  const int r0 = bm + waveR * 64 + quad * 4;
  const int c0 = bn + waveC * 64 + l15;
#pragma unroll
  for (int i = 0; i < 4; ++i)
#pragma unroll
    for (int r = 0; r < 4; ++r) {
      int row = r0 + i * 16 + r;
#pragma unroll
      for (int j = 0; j < 4; ++j) {
        int col = c0 + j * 16;
        float v = acc[i][j][r] + (rowb ? bp[row] : bp[col]);
        C[(size_t)row * ldc + col] = f2b(v);
      }
    }
}

// ---------------- BT-layout bf16 GEMM: C[m][n] = sum_k A[m][k]*B[n][k] -----
// 128x128 tile, BK=32, 256 threads (4 waves, each 64x64 via 4x4 MFMA 16x16x32)
// Round-6 structure (verified 57->50us): READS-BEFORE-STAGE with
// sched_barrier(0) fences — issuing the gl2lds stage before the ds_reads
// makes the compiler drain vmcnt(0) before the reads (LDS-DMA may-alias),
// killing the prefetch. Round-7's LDS XOR-swizzle removed all 4.19M bank
// conflicts but cost ~4% (T2 null at 2-phase; conflicts were hidden) —
// reverted.
enum { EPI_SCORE = 2, EPI_OUT = 3 };

template <int EPI>
__global__ __launch_bounds__(256, 2) void gemm_bt(
    const unsigned short* __restrict__ A, int lda, long long aBatch,
    const unsigned short* __restrict__ Bm, int ldb, long long bBatch,
    void* __restrict__ Cv, int ldc, long long cBatch,
    int K, float scale) {
  __shared__ unsigned short sA[2][128 * 32];
  __shared__ unsigned short sB[2][128 * 32];
  const int tid  = threadIdx.x;
  const int wave = tid >> 6;
  const int lane = tid & 63;
  const int l15  = lane & 15;
  const int quad = lane >> 4;
  const int waveR = wave >> 1, waveC = wave & 1;
  const int bm = blockIdx.x * 128;
  const int bn = blockIdx.y * 128;
  const int z  = blockIdx.z;
  A  += (long long)z * aBatch;
  Bm += (long long)z * bBatch;

  const unsigned short* gA0 = A  + (size_t)(bm + (tid >> 2)) * lda + (tid & 3) * 8;
  const unsigned short* gA1 = gA0 + (size_t)64 * lda;
  const unsigned short* gB0 = Bm + (size_t)(bn + (tid >> 2)) * ldb + (tid & 3) * 8;
  const unsigned short* gB1 = gB0 + (size_t)64 * ldb;
  const int ldsOff = wave * 64 * 8;   // wave-uniform LDS base; HW adds lane*16B

  f32x4 acc[4][4] = {};

  const int aro = (waveR * 64 + l15) * 32 + quad * 8;
  const int bro = (waveC * 64 + l15) * 32 + quad * 8;

  auto stage = [&](int c, int kt) {
    unsigned short* lA = sA[c] + ldsOff;
    unsigned short* lB = sB[c] + ldsOff;
    gl2lds16(gA0 + kt, lA);
    gl2lds16(gA1 + kt, lA + 256 * 8);
    gl2lds16(gB0 + kt, lB);
    gl2lds16(gB1 + kt, lB + 256 * 8);
  };

  stage(0, 0);
  int cur = 0;

  for (int kt = 0; kt < K; kt += 32) {
    __syncthreads();                 // buf[cur] landed (vmcnt0+lgkm0+barrier)
    short8 af[4], bf[4];
#pragma unroll
    for (int i = 0; i < 4; ++i) af[i] = *(const short8*)(sA[cur] + aro + i * 16 * 32);
#pragma unroll
    for (int j = 0; j < 4; ++j) bf[j] = *(const short8*)(sB[cur] + bro + j * 16 * 32);
    __builtin_amdgcn_sched_barrier(0);   // reads issued before any new DMA
    if (kt + 32 < K) stage(cur ^ 1, kt + 32);   // prefetch next tile
    __builtin_amdgcn_sched_barrier(0);   // stage issued before MFMA cluster
#pragma unroll
    for (int i = 0; i < 4; ++i)
#pragma unroll
      for (int j = 0; j < 4; ++j)
        acc[i][j] = __builtin_amdgcn_mfma_f32_16x16x32_bf16(af[i], bf[j], acc[i][j], 0, 0, 0);
    cur ^= 1;
  }

  // C/D layout: col = lane&15, row = quad*4 + reg
  const int r0 = bm + waveR * 64 + quad * 4;
  const int c0 = bn + waveC * 64 + l15;

  if constexpr (EPI == EPI_SCORE) {
    unsigned short* Cz = (unsigned short*)Cv + (long long)z * cBatch;
#pragma unroll
    for (int i = 0; i < 4; ++i)
#pragma unroll
      for (int r = 0; r < 4; ++r) {
        int row = r0 + i * 16 + r;
#pragma unroll
        for (int j = 0; j < 4; ++j) {
          int col = c0 + j * 16;
          Cz[(size_t)row * ldc + col] = f2b(acc[i][j][r] * scale);
        }
      }
  } else {
    float* Cz = (float*)Cv + (long long)z * cBatch;
#pragma unroll
    for (int i = 0; i < 4; ++i)
#pragma unroll
      for (int r = 0; r < 4; ++r) {
        int row = r0 + i * 16 + r;
#pragma unroll
        for (int j = 0; j < 4; ++j) {
          int col = c0 + j * 16;
          Cz[(size_t)row * ldc + col] = acc[i][j][r];
        }
      }
  }
}

// ------- row softmax: bf16 scores + raw mask (dtype self-probed) -> bf16 P --
__global__ __launch_bounds__(256) void softmax_rows(const unsigned short* __restrict__ Sc,
                                                    const void* __restrict__ mask,
                                                    unsigned short* __restrict__ P) {
  const size_t r = blockIdx.x;
  const unsigned short* src = Sc + r * SS;
  unsigned short* dst = P + r * SS;
  const int tid = threadIdx.x;
  const int wave = tid >> 6, lane = tid & 63;
  __shared__ int anyv[4];
  __shared__ float red[8];

  // dtype probe: first 256 words are inside row 0 for both layouts.
  // i32 bools -> all words 0/1. u8 packed bools -> word >1 w.p. 7/8.
  unsigned pw = ((const unsigned*)mask)[tid];
  unsigned long long bal = __ballot(pw > 1u);
  if (lane == 0) anyv[wave] = (bal != 0ULL) ? 1 : 0;
  __syncthreads();
  const bool isU8 = (anyv[0] | anyv[1] | anyv[2] | anyv[3]) != 0;

  // mask bits for cols [tid*8, tid*8+8)
  unsigned mbits = 0;
  if (isU8) {
    uint2 v = *(const uint2*)((const unsigned char*)mask + r * SS + tid * 8);
#pragma unroll
    for (int j = 0; j < 4; ++j) {
      mbits |= (((v.x >> (8 * j)) & 0xffu) ? 1u : 0u) << j;
      mbits |= (((v.y >> (8 * j)) & 0xffu) ? 1u : 0u) << (j + 4);
    }
  } else {
    const uint4* p = (const uint4*)((const int*)mask + r * SS + tid * 8);
    uint4 a = p[0], b = p[1];
    mbits = (a.x ? 1u : 0u) | ((a.y ? 1u : 0u) << 1) | ((a.z ? 1u : 0u) << 2) |
            ((a.w ? 1u : 0u) << 3) | ((b.x ? 1u : 0u) << 4) | ((b.y ? 1u : 0u) << 5) |
            ((b.z ? 1u : 0u) << 6) | ((b.w ? 1u : 0u) << 7);
  }

  union { unsigned short us[8]; uint4 v; } in;
  in.v = *(const uint4*)(src + tid * 8);
  float xs[8];
#pragma unroll
  for (int k = 0; k < 8; ++k)
    xs[k] = ((mbits >> k) & 1u) ? -1.0e9f : b2f(in.us[k]);
  float mx = xs[0];
#pragma unroll
  for (int k = 1; k < 8; ++k) mx = fmaxf(mx, xs[k]);
#pragma unroll
  for (int o = 32; o; o >>= 1) mx = fmaxf(mx, __shfl_xor(mx, o));
  if (lane == 0) red[wave] = mx;
  __syncthreads();
  mx = fmaxf(fmaxf(red[0], red[1]), fmaxf(red[2], red[3]));
  float e[8], s = 0.f;
#pragma unroll
  for (int k = 0; k < 8; ++k) { e[k] = __expf(xs[k] - mx); s += e[k]; }
#pragma unroll
  for (int o = 32; o; o >>= 1) s += __shfl_xor(s, o);
  if (lane == 0) red[4 + wave] = s;
  __syncthreads();
  s = (red[4] + red[5]) + (red[6] + red[7]);
  float inv = 1.0f / s;
  union { unsigned short us[8]; uint4 v; } o;
#pragma unroll
  for (int k = 0; k < 8; ++k) o.us[k] = f2b(e[k] * inv);
  *(uint4*)(dst + tid * 8) = o.v;
}

extern "C" void kernel_launch(void* const* d_in, const int* in_sizes, int n_in,
                              void* d_out, int out_size, void* d_ws, size_t ws_size,
                              hipStream_t stream) {
  const float* query = (const float*)d_in[0];
  const float* key   = (const float*)d_in[1];
  const float* value = (const float*)d_in[2];
  const void*  mask  = d_in[3];                 // bool: u8 or i32, self-probed
  const float* Wq = (const float*)d_in[4];
  const float* bq = (const float*)d_in[5];
  const float* Wk = (const float*)d_in[6];
  const float* bk = (const float*)d_in[7];
  const float* Wv = (const float*)d_in[8];
  const float* bv = (const float*)d_in[9];
  float* out = (float*)d_out;

  char* ws = (char*)d_ws;
  const size_t MB = 1024 * 1024;
  unsigned short* qb  = (unsigned short*)(ws + 54 * MB);   // q proj bf16, 16MB
  unsigned short* kb  = (unsigned short*)(ws + 70 * MB);   // (= qb + 8388608)
  unsigned short* vT  = (unsigned short*)(ws + 86 * MB);   // v^T [1024][8192] bf16
  unsigned short* Sc  = (unsigned short*)(ws + 102 * MB);  // scores bf16, 32MB
  unsigned short* P   = (unsigned short*)(ws + 134 * MB);  // softmax bf16, 32MB

  dim3 blk(256);

  // q/k projection + v^T projection, f32 inputs, one dispatch (z=0:q,1:k,2:vT)
  proj_f32<<<dim3(64, 8, 3), blk, 0, stream>>>(
      query, key, value, Wq, Wk, Wv, bq, bk, bv, qb, vT);

  // scores[b][m][n] = (q_m . k_n) / 32   (bf16, unmasked)
  gemm_bt<EPI_SCORE><<<dim3(16, 16, BB), blk, 0, stream>>>(
      qb, 1024, (long long)SS * 1024, kb, 1024, (long long)SS * 1024,
      Sc, SS, (long long)SS * SS, 1024, 0.03125f);

  // P = softmax(mask ? -1e9 : scores) rows, bf16
  softmax_rows<<<dim3(BB * SS), blk, 0, stream>>>(Sc, mask, P);

  // out[b][m][n] = sum_k P[m][k] * vT[n][k]   (fp32 out)
  gemm_bt<EPI_OUT><<<dim3(16, 8, BB), blk, 0, stream>>>(
      P, SS, (long long)SS * SS, vT, 8192, (long long)SS,
      out, 1024, (long long)SS * 1024, SS, 1.f);
}

// Round 9
// 356.828 us; speedup vs baseline: 1.2048x; 1.2048x over previous
//
#include <hip/hip_runtime.h>

// Problem constants
#define BB 4
#define SS 2048
#define DD 1024   // DIM_IN = DIM_Q = DIM_V = 1024

typedef __attribute__((ext_vector_type(8))) short short8;
typedef __attribute__((ext_vector_type(4))) float f32x4;

__device__ __forceinline__ unsigned short f2b(float f) {
  unsigned u = __builtin_bit_cast(unsigned, f);
  u += 0x7fffu + ((u >> 16) & 1u);   // RNE
  return (unsigned short)(u >> 16);
}
__device__ __forceinline__ float b2f(unsigned short us) {
  unsigned u = (unsigned)us << 16;
  return __builtin_bit_cast(float, u);
}

__device__ __forceinline__ void gl2lds16(const void* g, void* l) {
  __builtin_amdgcn_global_load_lds(
      (__attribute__((address_space(1))) unsigned int*)(void*)(size_t)(uintptr_t)g,
      (__attribute__((address_space(3))) unsigned int*)l, 16, 0, 0);
}

// -------- fp32 -> bf16 convert for 3 inputs (x<4096) and 3 weights (x>=4096)
// Round-6 version (32B/thread, measured 49.8us; the 64B/thread variant
// regressed to 53.5 in round 7 — occupancy drop, no MLP gain).
// Round-8's attempt to eliminate this dispatch entirely via f32 reg-staging
// in the projection GEMM regressed 78->192us (vmcnt(0)-after-MFMA stall +
// 128 f2b VALU/iter at 2 blocks/CU; MfmaUtil 10.9%) — reverted.
__global__ __launch_bounds__(256) void cvt_all(
    const float* __restrict__ q, const float* __restrict__ k, const float* __restrict__ v,
    const float* __restrict__ wq, const float* __restrict__ wk, const float* __restrict__ wv,
    unsigned short* __restrict__ qo, unsigned short* __restrict__ ko, unsigned short* __restrict__ vo,
    unsigned short* __restrict__ wqo, unsigned short* __restrict__ wko, unsigned short* __restrict__ wvo) {
  const int z = blockIdx.z;
  const float* s;
  unsigned short* d;
  size_t i;
  if (blockIdx.x < 4096) {
    s = z == 0 ? q : (z == 1 ? k : v);
    d = z == 0 ? qo : (z == 1 ? ko : vo);
    i = (size_t)blockIdx.x * 2048 + threadIdx.x * 8;
  } else {
    s = z == 0 ? wq : (z == 1 ? wk : wv);
    d = z == 0 ? wqo : (z == 1 ? wko : wvo);
    i = (size_t)(blockIdx.x - 4096) * 2048 + threadIdx.x * 8;
  }
  float4 a = *(const float4*)(s + i);
  float4 b = *(const float4*)(s + i + 4);
  union { unsigned short us[8]; uint4 v4; } o;
  o.us[0] = f2b(a.x); o.us[1] = f2b(a.y); o.us[2] = f2b(a.z); o.us[3] = f2b(a.w);
  o.us[4] = f2b(b.x); o.us[5] = f2b(b.y); o.us[6] = f2b(b.z); o.us[7] = f2b(b.w);
  *(uint4*)(d + i) = o.v4;
}

// ---------------- BT-layout bf16 GEMM core (round-6, verified 57->50us) ----
// 128x128 tile, BK=32, 256 threads (4 waves, each 64x64 via 4x4 MFMA 16x16x32)
// READS-BEFORE-STAGE with sched_barrier(0) fences: issuing the gl2lds stage
// before the ds_reads makes the compiler drain vmcnt(0) before the reads
// (LDS-DMA may-alias), killing the prefetch (rounds 0/5: 57us; round 6: 50).
// Round-7 LDS XOR-swizzle: conflicts 4.19M->0 but ~4% slower (hidden at
// 2-phase) — not used.
#define GEMM_BODY(A_, lda_, B_, ldb_, KK)                                       \
  __shared__ unsigned short sA[2][128 * 32];                                    \
  __shared__ unsigned short sB[2][128 * 32];                                    \
  const int tid  = threadIdx.x;                                                 \
  const int wave = tid >> 6;                                                    \
  const int lane = tid & 63;                                                    \
  const int l15  = lane & 15;                                                   \
  const int quad = lane >> 4;                                                   \
  const int waveR = wave >> 1, waveC = wave & 1;                                \
  const unsigned short* gA0 = A_ + (size_t)(bm + (tid >> 2)) * lda_ + (tid & 3) * 8; \
  const unsigned short* gA1 = gA0 + (size_t)64 * lda_;                          \
  const unsigned short* gB0 = B_ + (size_t)(bn + (tid >> 2)) * ldb_ + (tid & 3) * 8; \
  const unsigned short* gB1 = gB0 + (size_t)64 * ldb_;                          \
  const int ldsOff = wave * 64 * 8;                                             \
  f32x4 acc[4][4] = {};                                                         \
  const int aro = (waveR * 64 + l15) * 32 + quad * 8;                           \
  const int bro = (waveC * 64 + l15) * 32 + quad * 8;                           \
  auto stage = [&](int c, int kt) {                                             \
    unsigned short* lA = sA[c] + ldsOff;                                        \
    unsigned short* lB = sB[c] + ldsOff;                                        \
    gl2lds16(gA0 + kt, lA);                                                     \
    gl2lds16(gA1 + kt, lA + 256 * 8);                                           \
    gl2lds16(gB0 + kt, lB);                                                     \
    gl2lds16(gB1 + kt, lB + 256 * 8);                                           \
  };                                                                            \
  stage(0, 0);                                                                  \
  int cur = 0;                                                                  \
  for (int kt = 0; kt < (KK); kt += 32) {                                       \
    __syncthreads();                                                            \
    short8 af[4], bf[4];                                                        \
    _Pragma("unroll")                                                           \
    for (int i = 0; i < 4; ++i) af[i] = *(const short8*)(sA[cur] + aro + i * 16 * 32); \
    _Pragma("unroll")                                                           \
    for (int j = 0; j < 4; ++j) bf[j] = *(const short8*)(sB[cur] + bro + j * 16 * 32); \
    __builtin_amdgcn_sched_barrier(0);                                          \
    if (kt + 32 < (KK)) stage(cur ^ 1, kt + 32);                                \
    __builtin_amdgcn_sched_barrier(0);                                          \
    _Pragma("unroll")                                                           \
    for (int i = 0; i < 4; ++i)                                                 \
      _Pragma("unroll")                                                         \
      for (int j = 0; j < 4; ++j)                                               \
        acc[i][j] = __builtin_amdgcn_mfma_f32_16x16x32_bf16(af[i], bf[j], acc[i][j], 0, 0, 0); \
    cur ^= 1;                                                                   \
  }                                                                             \
  const int r0 = bm + waveR * 64 + quad * 4;                                    \
  const int c0 = bn + waveC * 64 + l15;
// C/D layout: col = lane&15, row = quad*4 + reg

// ===== merged projection dispatch (round-9): q-proj, k-proj, vT in ONE =====
// grid (64,8,3): z=0: qb[m][f]=query.Wq^T+bq; z=1: kb (same shapes);
// z=2: vT[n][m]=Wv.value^T+bv[n] (bm=y*128 over 1024 Wv-rows, bn=x*128 over
// 8192 m, ldc=8192, row-bias). 1536 blocks = exactly 3 CU-fill rounds
// (was 2 dispatches: 1024-block + 512-block, with a ~10us boundary between).
__global__ __launch_bounds__(256, 2) void proj_all(
    const unsigned short* __restrict__ qin, const unsigned short* __restrict__ kin,
    const unsigned short* __restrict__ vin,
    const unsigned short* __restrict__ Wqb, const unsigned short* __restrict__ Wkb,
    const unsigned short* __restrict__ Wvb,
    const float* __restrict__ bq, const float* __restrict__ bk,
    const float* __restrict__ bv,
    unsigned short* __restrict__ qkb,   // qb at +0, kb at +8388608 shorts
    unsigned short* __restrict__ vT) {
  const int z = blockIdx.z;
  const unsigned short *Ap, *Bp; const float* bp;
  unsigned short* C; int ldc, bm, bn; bool rowb;
  if (z == 2) {
    Ap = Wvb; Bp = vin; bp = bv; C = vT; ldc = 8192; rowb = true;
    bm = blockIdx.y * 128; bn = blockIdx.x * 128;
  } else {
    Ap = z ? kin : qin; Bp = z ? Wkb : Wqb; bp = z ? bk : bq;
    C = qkb + (size_t)z * 8388608; ldc = 1024; rowb = false;
    bm = blockIdx.x * 128; bn = blockIdx.y * 128;
  }

  GEMM_BODY(Ap, 1024, Bp, 1024, 1024)

#pragma unroll
  for (int i = 0; i < 4; ++i)
#pragma unroll
    for (int r = 0; r < 4; ++r) {
      int row = r0 + i * 16 + r;
#pragma unroll
      for (int j = 0; j < 4; ++j) {
        int col = c0 + j * 16;
        float v = acc[i][j][r] + (rowb ? bp[row] : bp[col]);
        C[(size_t)row * ldc + col] = f2b(v);
      }
    }
}

// ===== scores / out GEMMs (round-6, unchanged) =============================
enum { EPI_SCORE = 2, EPI_OUT = 3 };

template <int EPI>
__global__ __launch_bounds__(256, 2) void gemm_bt(
    const unsigned short* __restrict__ A, int lda, long long aBatch,
    const unsigned short* __restrict__ Bm, int ldb, long long bBatch,
    void* __restrict__ Cv, int ldc, long long cBatch,
    int K, float scale) {
  const int bm = blockIdx.x * 128;
  const int bn = blockIdx.y * 128;
  const int z  = blockIdx.z;
  const unsigned short* Az = A  + (long long)z * aBatch;
  const unsigned short* Bz = Bm + (long long)z * bBatch;

  GEMM_BODY(Az, lda, Bz, ldb, K)

  if constexpr (EPI == EPI_SCORE) {
    unsigned short* Cz = (unsigned short*)Cv + (long long)z * cBatch;
#pragma unroll
    for (int i = 0; i < 4; ++i)
#pragma unroll
      for (int r = 0; r < 4; ++r) {
        int row = r0 + i * 16 + r;
#pragma unroll
        for (int j = 0; j < 4; ++j) {
          int col = c0 + j * 16;
          Cz[(size_t)row * ldc + col] = f2b(acc[i][j][r] * scale);
        }
      }
  } else {
    float* Cz = (float*)Cv + (long long)z * cBatch;
#pragma unroll
    for (int i = 0; i < 4; ++i)
#pragma unroll
      for (int r = 0; r < 4; ++r) {
        int row = r0 + i * 16 + r;
#pragma unroll
        for (int j = 0; j < 4; ++j) {
          int col = c0 + j * 16;
          Cz[(size_t)row * ldc + col] = acc[i][j][r];
        }
      }
  }
}

// ------- row softmax: bf16 scores + raw mask (dtype self-probed) -> bf16 P --
__global__ __launch_bounds__(256) void softmax_rows(const unsigned short* __restrict__ Sc,
                                                    const void* __restrict__ mask,
                                                    unsigned short* __restrict__ P) {
  const size_t r = blockIdx.x;
  const unsigned short* src = Sc + r * SS;
  unsigned short* dst = P + r * SS;
  const int tid = threadIdx.x;
  const int wave = tid >> 6, lane = tid & 63;
  __shared__ int anyv[4];
  __shared__ float red[8];

  // dtype probe: first 256 words are inside row 0 for both layouts.
  // i32 bools -> all words 0/1. u8 packed bools -> word >1 w.p. 7/8.
  unsigned pw = ((const unsigned*)mask)[tid];
  unsigned long long bal = __ballot(pw > 1u);
  if (lane == 0) anyv[wave] = (bal != 0ULL) ? 1 : 0;
  __syncthreads();
  const bool isU8 = (anyv[0] | anyv[1] | anyv[2] | anyv[3]) != 0;

  // mask bits for cols [tid*8, tid*8+8)
  unsigned mbits = 0;
  if (isU8) {
    uint2 v = *(const uint2*)((const unsigned char*)mask + r * SS + tid * 8);
#pragma unroll
    for (int j = 0; j < 4; ++j) {
      mbits |= (((v.x >> (8 * j)) & 0xffu) ? 1u : 0u) << j;
      mbits |= (((v.y >> (8 * j)) & 0xffu) ? 1u : 0u) << (j + 4);
    }
  } else {
    const uint4* p = (const uint4*)((const int*)mask + r * SS + tid * 8);
    uint4 a = p[0], b = p[1];
    mbits = (a.x ? 1u : 0u) | ((a.y ? 1u : 0u) << 1) | ((a.z ? 1u : 0u) << 2) |
            ((a.w ? 1u : 0u) << 3) | ((b.x ? 1u : 0u) << 4) | ((b.y ? 1u : 0u) << 5) |
            ((b.z ? 1u : 0u) << 6) | ((b.w ? 1u : 0u) << 7);
  }

  union { unsigned short us[8]; uint4 v; } in;
  in.v = *(const uint4*)(src + tid * 8);
  float xs[8];
#pragma unroll
  for (int k = 0; k < 8; ++k)
    xs[k] = ((mbits >> k) & 1u) ? -1.0e9f : b2f(in.us[k]);
  float mx = xs[0];
#pragma unroll
  for (int k = 1; k < 8; ++k) mx = fmaxf(mx, xs[k]);
#pragma unroll
  for (int o = 32; o; o >>= 1) mx = fmaxf(mx, __shfl_xor(mx, o));
  if (lane == 0) red[wave] = mx;
  __syncthreads();
  mx = fmaxf(fmaxf(red[0], red[1]), fmaxf(red[2], red[3]));
  float e[8], s = 0.f;
#pragma unroll
  for (int k = 0; k < 8; ++k) { e[k] = __expf(xs[k] - mx); s += e[k]; }
#pragma unroll
  for (int o = 32; o; o >>= 1) s += __shfl_xor(s, o);
  if (lane == 0) red[4 + wave] = s;
  __syncthreads();
  s = (red[4] + red[5]) + (red[6] + red[7]);
  float inv = 1.0f / s;
  union { unsigned short us[8]; uint4 v; } o;
#pragma unroll
  for (int k = 0; k < 8; ++k) o.us[k] = f2b(e[k] * inv);
  *(uint4*)(dst + tid * 8) = o.v;
}

extern "C" void kernel_launch(void* const* d_in, const int* in_sizes, int n_in,
                              void* d_out, int out_size, void* d_ws, size_t ws_size,
                              hipStream_t stream) {
  const float* query = (const float*)d_in[0];
  const float* key   = (const float*)d_in[1];
  const float* value = (const float*)d_in[2];
  const void*  mask  = d_in[3];                 // bool: u8 or i32, self-probed
  const float* Wq = (const float*)d_in[4];
  const float* bq = (const float*)d_in[5];
  const float* Wk = (const float*)d_in[6];
  const float* bk = (const float*)d_in[7];
  const float* Wv = (const float*)d_in[8];
  const float* bv = (const float*)d_in[9];
  float* out = (float*)d_out;

  char* ws = (char*)d_ws;
  const size_t MB = 1024 * 1024;
  unsigned short* qin = (unsigned short*)(ws + 0 * MB);    // 8192x1024 bf16, 16MB
  unsigned short* kin = (unsigned short*)(ws + 16 * MB);
  unsigned short* vin = (unsigned short*)(ws + 32 * MB);
  unsigned short* Wqb = (unsigned short*)(ws + 48 * MB);   // 1024x1024 bf16, 2MB
  unsigned short* Wkb = (unsigned short*)(ws + 50 * MB);
  unsigned short* Wvb = (unsigned short*)(ws + 52 * MB);
  unsigned short* qb  = (unsigned short*)(ws + 54 * MB);   // q proj bf16, 16MB
  unsigned short* kb  = (unsigned short*)(ws + 70 * MB);   // (= qb + 8388608)
  unsigned short* vT  = (unsigned short*)(ws + 86 * MB);   // v^T [1024][8192] bf16
  unsigned short* Sc  = (unsigned short*)(ws + 102 * MB);  // scores bf16, 32MB
  unsigned short* P   = (unsigned short*)(ws + 134 * MB);  // softmax bf16, 32MB

  dim3 blk(256);

  // fp32 -> bf16 for all six tensors (one dispatch)
  cvt_all<<<dim3(4608, 1, 3), blk, 0, stream>>>(
      query, key, value, Wq, Wk, Wv, qin, kin, vin, Wqb, Wkb, Wvb);

  // q-proj + k-proj + v^T-proj, one dispatch (1536 blocks = 3 CU-fill rounds)
  proj_all<<<dim3(64, 8, 3), blk, 0, stream>>>(
      qin, kin, vin, Wqb, Wkb, Wvb, bq, bk, bv, qb, vT);

  // scores[b][m][n] = (q_m . k_n) / 32   (bf16, unmasked)
  gemm_bt<EPI_SCORE><<<dim3(16, 16, BB), blk, 0, stream>>>(
      qb, 1024, (long long)SS * 1024, kb, 1024, (long long)SS * 1024,
      Sc, SS, (long long)SS * SS, 1024, 0.03125f);

  // P = softmax(mask ? -1e9 : scores) rows, bf16
  softmax_rows<<<dim3(BB * SS), blk, 0, stream>>>(Sc, mask, P);

  // out[b][m][n] = sum_k P[m][k] * vT[n][k]   (fp32 out)
  gemm_bt<EPI_OUT><<<dim3(16, 8, BB), blk, 0, stream>>>(
      P, SS, (long long)SS * SS, vT, 8192, (long long)SS,
      out, 1024, (long long)SS * 1024, SS, 1.f);
}